// Round 2
// baseline (975.184 us; speedup 1.0000x reference)
//
#include <hip/hip_runtime.h>
#include <hip/hip_bf16.h>
#include <stdint.h>

typedef __hip_bfloat16 bf16;
typedef __bf16 bf16x8 __attribute__((ext_vector_type(8)));
typedef float floatx4 __attribute__((ext_vector_type(4)));

#define AS_LDS __attribute__((address_space(3)))
#define AS_GLB __attribute__((address_space(1)))

__device__ __forceinline__ void gload_lds16(const bf16* g, bf16* l) {
    __builtin_amdgcn_global_load_lds((const AS_GLB void*)g, (AS_LDS void*)l, 16, 0, 0);
}

// ---------- dtype probe: *flag = 1 if x is fp32, 0 if bf16 ----------
__global__ void probe_dtype(const float* __restrict__ x, int* __restrict__ flag) {
    __shared__ int cnt;
    if (threadIdx.x == 0) cnt = 0;
    __syncthreads();
    int ok = 0;
    for (int i = threadIdx.x; i < 4096; i += 256) {
        float v = x[i];
        if (v == v && fabsf(v) < 1.0e3f) ok++;
    }
    atomicAdd(&cnt, ok);
    __syncthreads();
    if (threadIdx.x == 0) *flag = (cnt > 2048) ? 1 : 0;
}

// ---------- convert raw (fp32 or bf16 per flag) -> canonical bf16 ----------
__global__ __launch_bounds__(256) void convert_to_bf16(
    const void* __restrict__ in, bf16* __restrict__ out, long n,
    const int* __restrict__ flag)
{
    long i = ((long)blockIdx.x * 256 + threadIdx.x) * 8;
    if (i >= n) return;
    bf16 o[8];
    if (*flag) {
        const float* p = (const float*)in + i;
        float4 a = *(const float4*)p;
        float4 b = *(const float4*)(p + 4);
        o[0] = __float2bfloat16(a.x); o[1] = __float2bfloat16(a.y);
        o[2] = __float2bfloat16(a.z); o[3] = __float2bfloat16(a.w);
        o[4] = __float2bfloat16(b.x); o[5] = __float2bfloat16(b.y);
        o[6] = __float2bfloat16(b.z); o[7] = __float2bfloat16(b.w);
    } else {
        *(float4*)o = *(const float4*)((const bf16*)in + i);
    }
    *(float4*)&out[i] = *(float4*)o;
}

// ---------- emit canonical bf16 -> d_out in flag dtype (fallback tiers) ----
__global__ __launch_bounds__(256) void emit_out(
    const bf16* __restrict__ in, void* __restrict__ out, long n,
    const int* __restrict__ flag)
{
    long i = ((long)blockIdx.x * 256 + threadIdx.x) * 8;
    if (i >= n) return;
    bf16 v[8];
    *(float4*)v = *(const float4*)&in[i];
    if (*flag) {
        float* o = (float*)out + i;
        float4 a, b;
        a.x = __bfloat162float(v[0]); a.y = __bfloat162float(v[1]);
        a.z = __bfloat162float(v[2]); a.w = __bfloat162float(v[3]);
        b.x = __bfloat162float(v[4]); b.y = __bfloat162float(v[5]);
        b.z = __bfloat162float(v[6]); b.w = __bfloat162float(v[7]);
        *(float4*)o = a;
        *(float4*)(o + 4) = b;
    } else {
        *(float4*)((bf16*)out + i) = *(float4*)v;
    }
}

// ---------- transpose raw-dtype input -> bf16 output ----------
__global__ __launch_bounds__(256) void transpose_any(
    const void* __restrict__ inv, bf16* __restrict__ out,
    int ldin, int ldout, const int* __restrict__ flag)
{
    __shared__ bf16 tile[64][80];
    const int fp32 = *flag;
    const int c0 = blockIdx.x * 64;
    const int r0 = blockIdx.y * 64;
    const int tid = threadIdx.x;
#pragma unroll
    for (int it = 0; it < 2; ++it) {
        int ch = tid + it * 256;
        int r = ch >> 3, c = (ch & 7) * 8;
        long eidx = (long)(r0 + r) * ldin + (c0 + c);
        if (fp32) {
            const float* p = (const float*)inv + eidx;
            float4 a = *(const float4*)p;
            float4 b = *(const float4*)(p + 4);
            bf16 o[8];
            o[0] = __float2bfloat16(a.x); o[1] = __float2bfloat16(a.y);
            o[2] = __float2bfloat16(a.z); o[3] = __float2bfloat16(a.w);
            o[4] = __float2bfloat16(b.x); o[5] = __float2bfloat16(b.y);
            o[6] = __float2bfloat16(b.z); o[7] = __float2bfloat16(b.w);
            *(float4*)&tile[r][c] = *(float4*)o;
        } else {
            *(float4*)&tile[r][c] = *(const float4*)((const bf16*)inv + eidx);
        }
    }
    __syncthreads();
#pragma unroll
    for (int it = 0; it < 2; ++it) {
        int ch = tid + it * 256;
        int oc = ch >> 3, rb = (ch & 7) * 8;
        bf16 tmp[8];
#pragma unroll
        for (int i = 0; i < 8; ++i) tmp[i] = tile[rb + i][oc];
        *(float4*)&out[(long)(c0 + oc) * ldout + r0 + rb] = *(float4*)tmp;
    }
}

// ---------- pure-bf16 transpose (fallback tiers) ----------
__global__ __launch_bounds__(256) void transpose_bf16(
    const bf16* __restrict__ in, bf16* __restrict__ out,
    int ldin, int ldout,
    int nz1, long in_z1, long out_z1, long in_z2, long out_z2)
{
    __shared__ bf16 tile[64][80];
    const int z = blockIdx.z;
    const int z1 = z % nz1, z2 = z / nz1;
    in  += (long)z1 * in_z1 + (long)z2 * in_z2;
    out += (long)z1 * out_z1 + (long)z2 * out_z2;
    const int c0 = blockIdx.x * 64;
    const int r0 = blockIdx.y * 64;
    const int tid = threadIdx.x;
#pragma unroll
    for (int it = 0; it < 2; ++it) {
        int ch = tid + it * 256;
        int r = ch >> 3, c = (ch & 7) * 8;
        *(float4*)&tile[r][c] = *(const float4*)&in[(long)(r0 + r) * ldin + c0 + c];
    }
    __syncthreads();
#pragma unroll
    for (int it = 0; it < 2; ++it) {
        int ch = tid + it * 256;
        int oc = ch >> 3, rb = (ch & 7) * 8;
        bf16 tmp[8];
#pragma unroll
        for (int i = 0; i < 8; ++i) tmp[i] = tile[rb + i][oc];
        *(float4*)&out[(long)(c0 + oc) * ldout + r0 + rb] = *(float4*)tmp;
    }
}

// =====================================================================
// 256x256-tile 8-wave 8-phase GEMM (T2 swizzle + T3/T4 counted vmcnt +
// T5 setprio). C = A * Bt^T. K multiple of 128. M,N multiples of 256.
// MODE 1: C = exp(acc)            (QK scores)
// MODE 4: QKV projection epilogue (bias+scale for Q; V written transposed)
//
// LDS layout per operand: [buf=tile&1][khalf][256 rows][32 cols], each
// k-half contiguous (16 KB) so global_load_lds destinations stay linear
// (per-lane LDS offset decomposes to uniform + lane*16B exactly).
// Swizzle: logical chunk cl (8 elems) of row r lives at LDS chunk
// cl ^ ((r>>1)&3). Applied on the global SOURCE address during staging and
// on the ds_read address (involution, rule #21).
//
// Issue schedule (units = one (operand,khalf) = 2 global_load_lds):
//   prologue: A0k0 B0k0 A0k1 B0k1 A1k0 B1k0 ; vmcnt(4) ; barrier
//   iter (tiles t,t+1): P1:A(t+1)k1 P2:B(t+1)k1 P3:A(t+2)k0
//   P4:B(t+2)k0+vmcnt(4) P5:A(t+2)k1 P6:B(t+2)k1 P7:A(t+3)k0
//   P8:B(t+3)k0+vmcnt(4). Every ds_read's producer unit is landed by the
//   preceding vmcnt(4); every LDS-slot rewrite is issued >=1 barrier-pair
//   after its last reader.
// Rule #18: sched_barrier(0) after every waitcnt so MFMAs can't be
// hoisted above the lgkmcnt by the scheduler.
// =====================================================================
template <int MODE>
__global__ __launch_bounds__(512, 2) void gemm256(
    const bf16* __restrict__ A, const bf16* __restrict__ Bt,
    bf16* __restrict__ C, const bf16* __restrict__ bias,
    int lda, int ldb, int ldc,
    long az, long bz, long cz, int K, float scale, int qcols,
    bf16* __restrict__ Vt, int vcol0)
{
    __shared__ bf16 AsL[2][2][256 * 32];
    __shared__ bf16 BsL[2][2][256 * 32];

    const int tid  = threadIdx.x;
    const int lane = tid & 63;
    const int wave = tid >> 6;
    const int wr = wave >> 2;        // 0..1  row half of C tile
    const int wc = wave & 3;         // 0..3  col quarter of C tile
    const int lm = lane & 15;
    const int cl = lane >> 4;        // fragment k-chunk 0..3
    const long zz = blockIdx.z;
    A  += zz * az;
    Bt += zz * bz;
    C  += zz * cz;
    const int m0 = blockIdx.y * 256;
    const int n0 = blockIdx.x * 256;

    // per-lane swizzled ds_read offsets within a [256][32] k-half block
    int offA[8], offB[4];
#pragma unroll
    for (int i = 0; i < 8; ++i) {
        int row = wr * 128 + i * 16 + lm;
        offA[i] = row * 32 + ((cl ^ ((row >> 1) & 3)) << 3);
    }
#pragma unroll
    for (int j = 0; j < 4; ++j) {
        int row = wc * 64 + j * 16 + lm;
        offB[j] = row * 32 + ((cl ^ ((row >> 1) & 3)) << 3);
    }

    const int sr = lane >> 2;        // staging row-in-16
    const int sc = lane & 3;         // staging chunk
    const int NT = K >> 6;           // 64-wide K tiles (NT even)

    floatx4 acc[8][4];
#pragma unroll
    for (int i = 0; i < 8; ++i)
#pragma unroll
        for (int j = 0; j < 4; ++j)
            acc[i][j] = (floatx4){0.f, 0.f, 0.f, 0.f};

    // stage one (operand, khalf) unit of tile t: 2 x global_load_lds
    auto stageU = [&](int which, int t, int kh) {
        if (t >= NT) return;
        const bf16* G = which ? Bt : A;
        const int ldg  = which ? ldb : lda;
        const int g0   = which ? n0 : m0;
        bf16* lb = which ? &BsL[t & 1][kh][0] : &AsL[t & 1][kh][0];
        const int kcol = t * 64 + kh * 32;
#pragma unroll
        for (int ii = 0; ii < 2; ++ii) {
            int row = ii * 128 + wave * 16 + sr;
            int cg  = sc ^ ((row >> 1) & 3);   // pre-swizzled global chunk
            gload_lds16(G + (long)(g0 + row) * ldg + kcol + cg * 8,
                        lb + row * 32 + sc * 8);
        }
    };

    bf16x8 af[8], bfv[2];
    auto dsA = [&](int b, int kh) {
        const bf16* p = &AsL[b][kh][0];
#pragma unroll
        for (int i = 0; i < 8; ++i) af[i] = *(const bf16x8*)(p + offA[i]);
    };
    auto dsB = [&](int b, int kh, int nh) {
        const bf16* p = &BsL[b][kh][0];
        bfv[0] = *(const bf16x8*)(p + offB[nh * 2]);
        bfv[1] = *(const bf16x8*)(p + offB[nh * 2 + 1]);
    };
    auto mfmaQ = [&](int nh) {
        __builtin_amdgcn_s_setprio(1);
#pragma unroll
        for (int i = 0; i < 8; ++i) {
            acc[i][nh * 2] = __builtin_amdgcn_mfma_f32_16x16x32_bf16(
                af[i], bfv[0], acc[i][nh * 2], 0, 0, 0);
            acc[i][nh * 2 + 1] = __builtin_amdgcn_mfma_f32_16x16x32_bf16(
                af[i], bfv[1], acc[i][nh * 2 + 1], 0, 0, 0);
        }
        __builtin_amdgcn_s_setprio(0);
    };

#define BAR    __builtin_amdgcn_s_barrier()
#define SBZ    __builtin_amdgcn_sched_barrier(0)
#define LGKM0  do { asm volatile("s_waitcnt lgkmcnt(0)" ::: "memory"); SBZ; } while (0)
#define VM(n)  do { asm volatile("s_waitcnt vmcnt(" #n ")" ::: "memory"); SBZ; } while (0)

    // ---- prologue: tile0 (all), tile1 k0 ----
    stageU(0, 0, 0); stageU(1, 0, 0); stageU(0, 0, 1); stageU(1, 0, 1);
    stageU(0, 1, 0); stageU(1, 1, 0);
    VM(4);
    BAR;

    for (int t0 = 0; t0 < NT; t0 += 2) {
        const bool last = (t0 + 2 >= NT);
        // P1: tile t0, khalf0, nh0
        dsA(0, 0); dsB(0, 0, 0); stageU(0, t0 + 1, 1);
        BAR; LGKM0; mfmaQ(0); BAR;
        // P2: khalf0, nh1
        dsB(0, 0, 1); stageU(1, t0 + 1, 1);
        BAR; LGKM0; mfmaQ(1); BAR;
        // P3: khalf1, nh0
        dsA(0, 1); dsB(0, 1, 0); stageU(0, t0 + 2, 0);
        BAR; LGKM0; mfmaQ(0); BAR;
        // P4: khalf1, nh1  (+ K-tile boundary wait)
        dsB(0, 1, 1); stageU(1, t0 + 2, 0);
        BAR; LGKM0; mfmaQ(1);
        if (last) { VM(0); } else { VM(4); }
        BAR;
        // P5: tile t0+1, khalf0, nh0
        dsA(1, 0); dsB(1, 0, 0); stageU(0, t0 + 2, 1);
        BAR; LGKM0; mfmaQ(0); BAR;
        // P6
        dsB(1, 0, 1); stageU(1, t0 + 2, 1);
        BAR; LGKM0; mfmaQ(1); BAR;
        // P7: khalf1, nh0
        dsA(1, 1); dsB(1, 1, 0); stageU(0, t0 + 3, 0);
        BAR; LGKM0; mfmaQ(0); BAR;
        // P8
        dsB(1, 1, 1); stageU(1, t0 + 3, 0);
        BAR; LGKM0; mfmaQ(1);
        if (!last) { VM(4); }
        BAR;
    }
#undef BAR
#undef SBZ
#undef LGKM0
#undef VM

    // ---- epilogue ----
    const int cr = (lane >> 4) * 4;
    if constexpr (MODE == 1) {
#pragma unroll
        for (int j = 0; j < 4; ++j) {
            int col = n0 + wc * 64 + j * 16 + lm;
#pragma unroll
            for (int i = 0; i < 8; ++i)
#pragma unroll
                for (int r = 0; r < 4; ++r) {
                    int row = m0 + wr * 128 + i * 16 + cr + r;
                    C[(long)row * ldc + col] = __float2bfloat16(__expf(acc[i][j][r]));
                }
        }
    } else {   // MODE 4
        if (n0 >= vcol0) {
#pragma unroll
            for (int j = 0; j < 4; ++j) {
                int col = n0 + wc * 64 + j * 16 + lm;
                float bv = __bfloat162float(bias[col]);
                int eg = col - vcol0;
                bf16* vt = Vt + ((long)(eg >> 9) * 512 + (eg & 511)) * 2048;
#pragma unroll
                for (int i = 0; i < 8; ++i) {
                    int t0v = m0 + wr * 128 + i * 16 + cr;
                    bf16 pk[4];
#pragma unroll
                    for (int r = 0; r < 4; ++r)
                        pk[r] = __float2bfloat16(acc[i][j][r] + bv);
                    *(ushort4*)&vt[t0v] = *(ushort4*)pk;
                }
            }
        } else {
#pragma unroll
            for (int j = 0; j < 4; ++j) {
                int col = n0 + wc * 64 + j * 16 + lm;
                float bv = __bfloat162float(bias[col]);
                float sc2 = (col < qcols) ? scale : 1.0f;
#pragma unroll
                for (int i = 0; i < 8; ++i)
#pragma unroll
                    for (int r = 0; r < 4; ++r) {
                        int row = m0 + wr * 128 + i * 16 + cr + r;
                        C[(long)row * ldc + col] =
                            __float2bfloat16((acc[i][j][r] + bv) * sc2);
                    }
            }
        }
    }
}

// ---------- GEMM (bf16 in/out, fp32 acc), templated epilogue -------------
// MODE 0: C = (acc + bias) * (col<qcols ? scale : 1)
// MODE 1: C = exp(acc)
// MODE 2: C += acc   (tier-D accumulate)
// MODE 3: C = acc / L, L = row-sum of A via ones-MFMA (K spans full row)
// MODE 4: QKV projection with fused V-transpose
template <int MODE, bool SWAP = false>
__global__ __launch_bounds__(256) void gemm_bt(
    const bf16* __restrict__ A, const bf16* __restrict__ Bt,
    bf16* __restrict__ C, const bf16* __restrict__ bias,
    int lda, int ldb, int ldc,
    long az, long bz, long cz, int K, float scale, int qcols,
    bf16* __restrict__ Vt, int vcol0)
{
    __shared__ bf16 As[128 * 64];
    __shared__ bf16 Bs[128 * 64];

    const int tid  = threadIdx.x;
    const int lane = tid & 63;
    const int wave = tid >> 6;
    const int wx = wave & 1;
    const int wy = wave >> 1;
    const long zz = blockIdx.z;
    A  += zz * az;
    Bt += zz * bz;
    C  += zz * cz;
    const int bm = SWAP ? blockIdx.x : blockIdx.y;
    const int bn = SWAP ? blockIdx.y : blockIdx.x;
    const int m0 = bm * 128;
    const int n0 = bn * 128;

    const int lm = lane & 15;
    const int kq = (lane >> 4) * 8;

    floatx4 acc[4][4];
#pragma unroll
    for (int i = 0; i < 4; ++i)
#pragma unroll
        for (int j = 0; j < 4; ++j)
            acc[i][j] = (floatx4){0.f, 0.f, 0.f, 0.f};

    floatx4 accOnes[4];
    bf16x8 ones;
    if constexpr (MODE == 3) {
#pragma unroll
        for (int i = 0; i < 4; ++i) accOnes[i] = (floatx4){0.f, 0.f, 0.f, 0.f};
#pragma unroll
        for (int k = 0; k < 8; ++k) ones[k] = (__bf16)1.0f;
    }

    for (int kt = 0; kt < K; kt += 64) {
        __syncthreads();
#pragma unroll
        for (int it = 0; it < 4; ++it) {
            int ch = tid + it * 256;
            int r = ch >> 3;
            int c = (ch & 7) * 8;
            gload_lds16(A  + (long)(m0 + r) * lda + (kt + c), &As[ch * 8]);
            gload_lds16(Bt + (long)(n0 + r) * ldb + (kt + c), &Bs[ch * 8]);
        }
        __syncthreads();
#pragma unroll
        for (int kk = 0; kk < 64; kk += 32) {
            bf16x8 af[4], bfv[4];
#pragma unroll
            for (int i = 0; i < 4; ++i)
                af[i] = *(const bf16x8*)&As[(wy * 64 + i * 16 + lm) * 64 + kk + kq];
#pragma unroll
            for (int j = 0; j < 4; ++j)
                bfv[j] = *(const bf16x8*)&Bs[(wx * 64 + j * 16 + lm) * 64 + kk + kq];
#pragma unroll
            for (int i = 0; i < 4; ++i) {
#pragma unroll
                for (int j = 0; j < 4; ++j)
                    acc[i][j] = __builtin_amdgcn_mfma_f32_16x16x32_bf16(
                        af[i], bfv[j], acc[i][j], 0, 0, 0);
                if constexpr (MODE == 3)
                    accOnes[i] = __builtin_amdgcn_mfma_f32_16x16x32_bf16(
                        af[i], ones, accOnes[i], 0, 0, 0);
            }
        }
    }

    const int cr = (lane >> 4) * 4;
    if constexpr (MODE == 1) {
#pragma unroll
        for (int j = 0; j < 4; ++j) {
            int col = n0 + wx * 64 + j * 16 + lm;
#pragma unroll
            for (int i = 0; i < 4; ++i)
#pragma unroll
                for (int r = 0; r < 4; ++r) {
                    int row = m0 + wy * 64 + i * 16 + cr + r;
                    C[(long)row * ldc + col] = __float2bfloat16(__expf(acc[i][j][r]));
                }
        }
    } else if constexpr (MODE == 3) {
        floatx4 inv[4];
#pragma unroll
        for (int i = 0; i < 4; ++i)
#pragma unroll
            for (int r = 0; r < 4; ++r)
                inv[i][r] = 1.0f / accOnes[i][r];
#pragma unroll
        for (int j = 0; j < 4; ++j) {
            int col = n0 + wx * 64 + j * 16 + lm;
#pragma unroll
            for (int i = 0; i < 4; ++i)
#pragma unroll
                for (int r = 0; r < 4; ++r) {
                    int row = m0 + wy * 64 + i * 16 + cr + r;
                    C[(long)row * ldc + col] =
                        __float2bfloat16(acc[i][j][r] * inv[i][r]);
                }
        }
    } else if constexpr (MODE == 4) {
        if (n0 >= vcol0) {
#pragma unroll
            for (int j = 0; j < 4; ++j) {
                int col = n0 + wx * 64 + j * 16 + lm;
                float bv = __bfloat162float(bias[col]);
                int eg = col - vcol0;
                bf16* vt = Vt + ((long)(eg >> 9) * 512 + (eg & 511)) * 2048;
#pragma unroll
                for (int i = 0; i < 4; ++i) {
                    int t0 = m0 + wy * 64 + i * 16 + cr;
                    bf16 pk[4];
#pragma unroll
                    for (int r = 0; r < 4; ++r)
                        pk[r] = __float2bfloat16(acc[i][j][r] + bv);
                    *(ushort4*)&vt[t0] = *(ushort4*)pk;
                }
            }
        } else {
#pragma unroll
            for (int j = 0; j < 4; ++j) {
                int col = n0 + wx * 64 + j * 16 + lm;
                float bv = __bfloat162float(bias[col]);
                float sc = (col < qcols) ? scale : 1.0f;
#pragma unroll
                for (int i = 0; i < 4; ++i)
#pragma unroll
                    for (int r = 0; r < 4; ++r) {
                        int row = m0 + wy * 64 + i * 16 + cr + r;
                        C[(long)row * ldc + col] =
                            __float2bfloat16((acc[i][j][r] + bv) * sc);
                    }
            }
        }
    } else {
#pragma unroll
        for (int j = 0; j < 4; ++j) {
            int col = n0 + wx * 64 + j * 16 + lm;
            float bv = (MODE == 0 && bias) ? __bfloat162float(bias[col]) : 0.f;
            float sc = (col < qcols) ? scale : 1.0f;
#pragma unroll
            for (int i = 0; i < 4; ++i) {
#pragma unroll
                for (int r = 0; r < 4; ++r) {
                    int row = m0 + wy * 64 + i * 16 + cr + r;
                    long idx = (long)row * ldc + col;
                    float v;
                    if (MODE == 2) v = acc[i][j][r] + __bfloat162float(C[idx]);
                    else           v = (acc[i][j][r] + bv) * sc;
                    C[idx] = __float2bfloat16(v);
                }
            }
        }
    }
}

// ---------- split-K GEMM, bf16 partials (SWAP as above) ------------------
template <bool SWAP = false>
__global__ __launch_bounds__(256) void gemm_bt_splitk(
    const bf16* __restrict__ A, const bf16* __restrict__ Bt,
    bf16* __restrict__ P, int lda, int ldb, int ldp,
    long az, long bz, long pz, long skStride, int nsk, int Kc)
{
    __shared__ bf16 As[128 * 64];
    __shared__ bf16 Bs[128 * 64];

    const int tid  = threadIdx.x;
    const int lane = tid & 63;
    const int wave = tid >> 6;
    const int wx = wave & 1;
    const int wy = wave >> 1;
    const int zz = blockIdx.z;
    const int ks = zz % nsk;
    const int zh = zz / nsk;
    A  += (long)zh * az;
    Bt += (long)zh * bz;
    bf16* Pz = P + (long)zh * pz + (long)ks * skStride;
    const int bm = SWAP ? blockIdx.x : blockIdx.y;
    const int bn = SWAP ? blockIdx.y : blockIdx.x;
    const int m0 = bm * 128;
    const int n0 = bn * 128;
    const int k0 = ks * Kc;

    const int lm = lane & 15;
    const int kq = (lane >> 4) * 8;

    floatx4 acc[4][4];
#pragma unroll
    for (int i = 0; i < 4; ++i)
#pragma unroll
        for (int j = 0; j < 4; ++j)
            acc[i][j] = (floatx4){0.f, 0.f, 0.f, 0.f};

    for (int kt = k0; kt < k0 + Kc; kt += 64) {
        __syncthreads();
#pragma unroll
        for (int it = 0; it < 4; ++it) {
            int ch = tid + it * 256;
            int r = ch >> 3;
            int c = (ch & 7) * 8;
            gload_lds16(A  + (long)(m0 + r) * lda + (kt + c), &As[ch * 8]);
            gload_lds16(Bt + (long)(n0 + r) * ldb + (kt + c), &Bs[ch * 8]);
        }
        __syncthreads();
#pragma unroll
        for (int kk = 0; kk < 64; kk += 32) {
            bf16x8 af[4], bfv[4];
#pragma unroll
            for (int i = 0; i < 4; ++i)
                af[i] = *(const bf16x8*)&As[(wy * 64 + i * 16 + lm) * 64 + kk + kq];
#pragma unroll
            for (int j = 0; j < 4; ++j)
                bfv[j] = *(const bf16x8*)&Bs[(wx * 64 + j * 16 + lm) * 64 + kk + kq];
#pragma unroll
            for (int i = 0; i < 4; ++i)
#pragma unroll
                for (int j = 0; j < 4; ++j)
                    acc[i][j] = __builtin_amdgcn_mfma_f32_16x16x32_bf16(
                        af[i], bfv[j], acc[i][j], 0, 0, 0);
        }
    }

    const int cr = (lane >> 4) * 4;
#pragma unroll
    for (int j = 0; j < 4; ++j) {
        int col = n0 + wx * 64 + j * 16 + lm;
#pragma unroll
        for (int i = 0; i < 4; ++i)
#pragma unroll
            for (int r = 0; r < 4; ++r) {
                int row = m0 + wy * 64 + i * 16 + cr + r;
                Pz[(long)row * ldp + col] = __float2bfloat16(acc[i][j][r]);
            }
    }
}

// ---------- reduce 2 bf16 split-K partials + bias -> d_out in flag dtype ----
__global__ __launch_bounds__(256) void reduce_emit(
    const bf16* __restrict__ P, const bf16* __restrict__ bias,
    void* __restrict__ out, long MN, int N,
    const int* __restrict__ flag)
{
    long i = ((long)blockIdx.x * 256 + threadIdx.x) * 8;
    if (i >= MN) return;
    bf16 bb[8], a[8], b[8];
    *(float4*)bb = *(const float4*)&bias[i & (N - 1)];
    *(float4*)a  = *(const float4*)&P[i];
    *(float4*)b  = *(const float4*)&P[MN + i];
    float s[8];
#pragma unroll
    for (int k = 0; k < 8; ++k)
        s[k] = __bfloat162float(bb[k]) + __bfloat162float(a[k]) + __bfloat162float(b[k]);
    if (*flag) {
        float* o = (float*)out + i;
        float4 lo = {s[0], s[1], s[2], s[3]};
        float4 hi = {s[4], s[5], s[6], s[7]};
        *(float4*)o = lo;
        *(float4*)(o + 4) = hi;
    } else {
        bf16 o[8];
#pragma unroll
        for (int k = 0; k < 8; ++k) o[k] = __float2bfloat16(s[k]);
        *(float4*)&((bf16*)out)[i] = *(float4*)o;
    }
}

// ---------- reduce bf16 split-K partials + bias -> bf16 (fallback) ----------
__global__ __launch_bounds__(256) void reduce_splitk(
    const bf16* __restrict__ P, const bf16* __restrict__ bias,
    bf16* __restrict__ Out, long MN, int N, int SK)
{
    long i = ((long)blockIdx.x * 256 + threadIdx.x) * 8;
    if (i >= MN) return;
    float s[8];
    if (bias) {
        bf16 bb[8];
        *(float4*)bb = *(const float4*)&bias[i & (N - 1)];
#pragma unroll
        for (int k = 0; k < 8; ++k) s[k] = __bfloat162float(bb[k]);
    } else {
#pragma unroll
        for (int k = 0; k < 8; ++k) s[k] = 0.f;
    }
    for (int z = 0; z < SK; ++z) {
        bf16 a[8];
        *(float4*)a = *(const float4*)&P[(long)z * MN + i];
#pragma unroll
        for (int k = 0; k < 8; ++k) s[k] += __bfloat162float(a[k]);
    }
    bf16 o[8];
#pragma unroll
    for (int k = 0; k < 8; ++k) o[k] = __float2bfloat16(s[k]);
    *(float4*)&Out[i] = *(float4*)o;
}

// ---------- in-place softmax over rows of 2048 bf16 (fallback tiers) -----
__global__ __launch_bounds__(256) void softmax_rows2048(bf16* __restrict__ S)
{
    __shared__ float red[8];
    const long row = blockIdx.x;
    bf16* p = S + row * 2048;
    const int tid = threadIdx.x;
    float4 raw = *(const float4*)&p[tid * 8];
    bf16 vb[8];
    *(float4*)vb = raw;
    float v[8];
#pragma unroll
    for (int i = 0; i < 8; ++i) v[i] = __bfloat162float(vb[i]);
    float m = v[0];
#pragma unroll
    for (int i = 1; i < 8; ++i) m = fmaxf(m, v[i]);
#pragma unroll
    for (int o = 32; o > 0; o >>= 1) m = fmaxf(m, __shfl_xor(m, o));
    if ((tid & 63) == 0) red[tid >> 6] = m;
    __syncthreads();
    m = fmaxf(fmaxf(red[0], red[1]), fmaxf(red[2], red[3]));
    float s = 0.f;
#pragma unroll
    for (int i = 0; i < 8; ++i) { v[i] = __expf(v[i] - m); s += v[i]; }
#pragma unroll
    for (int o = 32; o > 0; o >>= 1) s += __shfl_xor(s, o);
    if ((tid & 63) == 0) red[4 + (tid >> 6)] = s;
    __syncthreads();
    s = (red[4] + red[5]) + (red[6] + red[7]);
    float inv = 1.f / s;
#pragma unroll
    for (int i = 0; i < 8; ++i) vb[i] = __float2bfloat16(v[i] * inv);
    *(float4*)&p[tid * 8] = *(float4*)vb;
}

extern "C" void kernel_launch(void* const* d_in, const int* in_sizes, int n_in,
                              void* d_out, int out_size, void* d_ws, size_t ws_size,
                              hipStream_t stream)
{
    const int Bb = 4, T = 2048, E = 512, H = 8;
    const int HE = H * E;            // 4096
    const int N3 = 3 * HE;           // 12288
    const int N2 = 2 * HE;           // 8192 (Q|K row width)
    const int M  = Bb * T;           // 8192
    const long NX = (long)M * E;     // 4,194,304

    // ---- size-signature input assignment (order-robust) ----
    const void* xr = nullptr;
    const void* Wr[4] = {nullptr, nullptr, nullptr, nullptr};
    const void* br[3] = {nullptr, nullptr, nullptr};
    const void* bor = nullptr;
    int nw = 0, nb = 0;
    for (int i = 0; i < n_in; ++i) {
        int s = in_sizes[i];
        if      (s == (int)NX)      xr = d_in[i];
        else if (s == E * HE)       { if (nw < 4) Wr[nw++] = d_in[i]; }
        else if (s == HE)           { if (nb < 3) br[nb++] = d_in[i]; }
        else if (s == E)            bor = d_in[i];
    }
    if (!xr || nw < 4 || nb < 3 || !bor) {
        xr = d_in[0]; Wr[0] = d_in[1]; br[0] = d_in[2]; Wr[1] = d_in[3];
        br[1] = d_in[4]; Wr[2] = d_in[5]; br[2] = d_in[6]; Wr[3] = d_in[7];
        bor = d_in[8];
    }

    const float qscale = 0.04419417382415922f;  // 1/sqrt(512)
    const int   QC = 1 << 30;
    dim3 blk(256);

    // ---- workspace layout (bf16 elements) ----
    bf16* pool = (bf16*)d_ws;
    int*  flag = (int*)(void*)pool;
    bf16* xc   = pool + 8;
    bf16* bqc  = xc  + NX;     // bq|bk|bv contiguous (stacked bias [12288])
    bf16* bkc  = bqc + HE;
    bf16* bvc  = bkc + HE;
    bf16* boc  = bvc + HE;
    bf16* WqT  = boc + E;      // WqT|WkT|WvT contiguous (stacked Bt [12288,512])
    const size_t w2m = (size_t)E * HE;
    bf16* WkT  = WqT + w2m;
    bf16* WvT  = WkT + w2m;
    bf16* WoT  = WvT + w2m;
    bf16* Ofin = WoT + w2m;
    bf16* p0   = Ofin + NX;    // tier region

    const size_t wsE    = ws_size / sizeof(bf16);
    const size_t fixedE = (size_t)(p0 - pool);
    const size_t wQK   = (size_t)T * N2;      // 16.8M el — per-batch Q|K
    const size_t wQKV  = (size_t)T * N3;      // 25.17M el (tier-B fallback)
    const size_t wBat  = (size_t)T * HE;      // 8.39M el
    const size_t wHd   = (size_t)T * E;       // 1.05M el
    const size_t sAll  = (size_t)H * T * T;   // 33.55M el
    const size_t sOne  = (size_t)T * T;
    const size_t wBig  = (size_t)M * HE;      // 33.55M el
    const size_t needB2 = fixedE + wQK + wBat + sAll + wBig;   // ~218 MB
    const size_t needB  = fixedE + wQKV + 2 * wBat + sAll;     // ~185 MB
    const size_t needC  = fixedE + 5 * wBat + sOne;
    const size_t needD  = fixedE + 5 * wHd  + sOne;
    if (wsE < needD) return;

    // ---- stage 0: dtype probe + canonicalize ----
    probe_dtype<<<dim3(1), blk, 0, stream>>>((const float*)xr, flag);
    convert_to_bf16<<<dim3((unsigned)((NX / 8 + 255) / 256)), blk, 0, stream>>>(
        xr, xc, NX, flag);
    convert_to_bf16<<<dim3(2), blk, 0, stream>>>(br[0], bqc, HE, flag);
    convert_to_bf16<<<dim3(2), blk, 0, stream>>>(br[1], bkc, HE, flag);
    convert_to_bf16<<<dim3(2), blk, 0, stream>>>(br[2], bvc, HE, flag);
    convert_to_bf16<<<dim3(1), blk, 0, stream>>>(bor, boc, E, flag);
    transpose_any<<<dim3(HE / 64, E / 64, 1), blk, 0, stream>>>(Wr[0], WqT, HE, E, flag);
    transpose_any<<<dim3(HE / 64, E / 64, 1), blk, 0, stream>>>(Wr[1], WkT, HE, E, flag);
    transpose_any<<<dim3(HE / 64, E / 64, 1), blk, 0, stream>>>(Wr[2], WvT, HE, E, flag);
    transpose_any<<<dim3(E / 64, HE / 64, 1), blk, 0, stream>>>(Wr[3], WoT, E, HE, flag);

    if (wsE >= needB2) {
        // ---- Tier B2'': 256² 8-phase for QKV+QK; 128² for PV/out-proj ----
        bf16* QKb = p0;                  // [t, 8192] = Q|K; aliased for P later
        bf16* Vtb = QKb + wQK;           // [h,e,t] — written by MODE-4 epilogue
        bf16* S   = Vtb + wBat;          // exp(scores) [h,t,s]
        bf16* Oatt = S + sAll;           // O_all [M, HE]

        for (int b = 0; b < Bb; ++b) {
            const bf16* xb = xc + (size_t)b * T * E;
            // merged QKV projection; V columns written transposed to Vtb
            gemm256<4><<<dim3(N3 / 256, T / 256, 1), dim3(512), 0, stream>>>(
                xb, WqT, QKb, bqc, E, E, N2, 0, 0, 0, E, qscale, HE, Vtb, N2);
            // QK: S = exp(Q K^T)
            gemm256<1><<<dim3(T / 256, T / 256, H), dim3(512), 0, stream>>>(
                QKb, QKb + HE, S, nullptr, N2, N2, T,
                (long)E, (long)E, (long)T * T, E, 1.f, QC, nullptr, 0);
            // PV: O = (S V) / rowsum(S). SWAP grid: x=m-tiles(16), y=n-tiles(4)
            gemm_bt<3, true><<<dim3(T / 128, E / 128, H), blk, 0, stream>>>(
                S, Vtb, Oatt + (size_t)b * T * HE, nullptr, T, T, HE,
                (long)T * T, (long)E * T, (long)E, T, 1.f, QC, nullptr, 0);
        }
        // out-proj: split-K=2, SWAP grid: x=m-tiles(64), y=n-tiles(4)
        gemm_bt_splitk<true><<<dim3(M / 128, E / 128, 2), blk, 0, stream>>>(
            Oatt, WoT, QKb, HE, HE, E, 0, 0, 0, (long)M * E, 2, HE / 2);
        reduce_emit<<<dim3((unsigned)((NX / 8 + 255) / 256)), blk, 0, stream>>>(
            QKb, boc, d_out, NX, E, flag);
        return;   // d_out written directly; no emit pass
    }

    if (wsE >= needB) {
        // ---- Tier B fallback: softmax path ----
        bf16* QKVb = p0;
        bf16* Vtb  = QKVb + wQKV;
        bf16* Oatt = Vtb + wBat;
        bf16* S    = Oatt + wBat;

        for (int b = 0; b < Bb; ++b) {
            const bf16* xb = xc + (size_t)b * T * E;
            gemm_bt<0><<<dim3(N3 / 128, T / 128, 1), blk, 0, stream>>>(
                xb, WqT, QKVb, bqc, E, E, N3, 0, 0, 0, E, qscale, HE, nullptr, 0);
            transpose_bf16<<<dim3(E / 64, T / 64, H), blk, 0, stream>>>(
                QKVb + 2 * HE, Vtb, N3, T, H, (long)E, (long)E * T, 0, 0);
            gemm_bt<0><<<dim3(T / 128, T / 128, H), blk, 0, stream>>>(
                QKVb, QKVb + HE, S, nullptr, N3, N3, T,
                (long)E, (long)E, (long)T * T, E, 1.f, QC, nullptr, 0);
            softmax_rows2048<<<dim3(H * T, 1, 1), blk, 0, stream>>>(S);
            gemm_bt<0><<<dim3(E / 128, T / 128, H), blk, 0, stream>>>(
                S, Vtb, Oatt, nullptr, T, T, HE,
                (long)T * T, (long)E * T, (long)E, T, 1.f, QC, nullptr, 0);
            gemm_bt_splitk<false><<<dim3(E / 128, T / 128, 8), blk, 0, stream>>>(
                Oatt, WoT, (bf16*)S, HE, HE, E, 0, 0, 0, (long)T * E, 8, HE / 8);
            reduce_splitk<<<dim3((unsigned)(((long)T * E / 8 + 255) / 256)), blk, 0, stream>>>(
                (bf16*)S, boc, Ofin + (size_t)b * T * E, (long)T * E, E, 8);
        }
    } else if (wsE >= needC) {
        // ---- Tier C fallback ----
        bf16* Qb  = p0;
        bf16* Kb  = Qb  + wBat;
        bf16* Vb  = Kb  + wBat;
        bf16* Vtb = Vb  + wBat;
        bf16* Ob  = Vtb + wBat;
        bf16* S   = Ob  + wBat;

        for (int b = 0; b < Bb; ++b) {
            const bf16* xb = xc + (size_t)b * T * E;
            gemm_bt<0><<<dim3(HE / 128, T / 128, 1), blk, 0, stream>>>(
                xb, WqT, Qb, bqc, E, E, HE, 0, 0, 0, E, qscale, QC, nullptr, 0);
            gemm_bt<0><<<dim3(HE / 128, T / 128, 1), blk, 0, stream>>>(
                xb, WkT, Kb, bkc, E, E, HE, 0, 0, 0, E, 1.f, QC, nullptr, 0);
            gemm_bt<0><<<dim3(HE / 128, T / 128, 1), blk, 0, stream>>>(
                xb, WvT, Vb, bvc, E, E, HE, 0, 0, 0, E, 1.f, QC, nullptr, 0);
            transpose_bf16<<<dim3(E / 64, T / 64, H), blk, 0, stream>>>(
                Vb, Vtb, HE, T, H, (long)E, (long)E * T, 0, 0);
            for (int h = 0; h < H; ++h) {
                gemm_bt<0><<<dim3(T / 128, T / 128, 1), blk, 0, stream>>>(
                    Qb + (size_t)h * E, Kb + (size_t)h * E, S, nullptr,
                    HE, HE, T, 0, 0, 0, E, 1.f, QC, nullptr, 0);
                softmax_rows2048<<<dim3(T, 1, 1), blk, 0, stream>>>(S);
                gemm_bt<0><<<dim3(E / 128, T / 128, 1), blk, 0, stream>>>(
                    S, Vtb + (size_t)h * E * T, Ob + (size_t)h * E, nullptr,
                    T, T, HE, 0, 0, 0, T, 1.f, QC, nullptr, 0);
            }
            gemm_bt<0><<<dim3(E / 128, T / 128, 1), blk, 0, stream>>>(
                Ob, WoT, Ofin + (size_t)b * T * E, boc,
                HE, HE, E, 0, 0, 0, HE, 1.f, QC, nullptr, 0);
        }
    } else {
        // ---- Tier D fallback ----
        bf16* Qh  = p0;
        bf16* Kh  = Qh  + wHd;
        bf16* Vh  = Kh  + wHd;
        bf16* Vth = Vh  + wHd;
        bf16* Oh  = Vth + wHd;
        bf16* S   = Oh  + wHd;

        for (int b = 0; b < Bb; ++b) {
            const bf16* xb = xc + (size_t)b * T * E;
            bf16* outb = Ofin + (size_t)b * T * E;
            for (int h = 0; h < H; ++h) {
                const size_t hw = (size_t)h * E * E;
                gemm_bt<0><<<dim3(E / 128, T / 128, 1), blk, 0, stream>>>(
                    xb, WqT + hw, Qh, bqc + (size_t)h * E, E, E, E,
                    0, 0, 0, E, qscale, QC, nullptr, 0);
                gemm_bt<0><<<dim3(E / 128, T / 128, 1), blk, 0, stream>>>(
                    xb, WkT + hw, Kh, bkc + (size_t)h * E, E, E, E,
                    0, 0, 0, E, 1.f, QC, nullptr, 0);
                gemm_bt<0><<<dim3(E / 128, T / 128, 1), blk, 0, stream>>>(
                    xb, WvT + hw, Vh, bvc + (size_t)h * E, E, E, E,
                    0, 0, 0, E, 1.f, QC, nullptr, 0);
                transpose_bf16<<<dim3(E / 64, T / 64, 1), blk, 0, stream>>>(
                    Vh, Vth, E, T, 1, 0, 0, 0, 0);
                gemm_bt<0><<<dim3(T / 128, T / 128, 1), blk, 0, stream>>>(
                    Qh, Kh, S, nullptr, E, E, T, 0, 0, 0, E, 1.f, QC, nullptr, 0);
                softmax_rows2048<<<dim3(T, 1, 1), blk, 0, stream>>>(S);
                gemm_bt<0><<<dim3(E / 128, T / 128, 1), blk, 0, stream>>>(
                    S, Vth, Oh, nullptr, T, T, E, 0, 0, 0, T, 1.f, QC, nullptr, 0);
                if (h == 0)
                    gemm_bt<0><<<dim3(E / 128, T / 128, 1), blk, 0, stream>>>(
                        Oh, WoT, outb, boc, E, HE, E, 0, 0, 0, E, 1.f, QC, nullptr, 0);
                else
                    gemm_bt<2><<<dim3(E / 128, T / 128, 1), blk, 0, stream>>>(
                        Oh, WoT + (size_t)h * E, outb, nullptr,
                        E, HE, E, 0, 0, 0, E, 1.f, QC, nullptr, 0);
            }
        }
    }

    // ---- emit in the probed dtype (fallback tiers only) ----
    emit_out<<<dim3((unsigned)((NX / 8 + 255) / 256)), blk, 0, stream>>>(
        Ofin, d_out, NX, flag);
}

// Round 4
// 875.313 us; speedup vs baseline: 1.1141x; 1.1141x over previous
//
#include <hip/hip_runtime.h>
#include <hip/hip_bf16.h>
#include <stdint.h>

typedef __hip_bfloat16 bf16;
typedef __bf16 bf16x8 __attribute__((ext_vector_type(8)));
typedef float floatx4 __attribute__((ext_vector_type(4)));

#define AS_LDS __attribute__((address_space(3)))
#define AS_GLB __attribute__((address_space(1)))

__device__ __forceinline__ void gload_lds16(const bf16* g, bf16* l) {
    __builtin_amdgcn_global_load_lds((const AS_GLB void*)g, (AS_LDS void*)l, 16, 0, 0);
}

// ---------- dtype probe: *flag = 1 if x is fp32, 0 if bf16 ----------
__global__ void probe_dtype(const float* __restrict__ x, int* __restrict__ flag) {
    __shared__ int cnt;
    if (threadIdx.x == 0) cnt = 0;
    __syncthreads();
    int ok = 0;
    for (int i = threadIdx.x; i < 4096; i += 256) {
        float v = x[i];
        if (v == v && fabsf(v) < 1.0e3f) ok++;
    }
    atomicAdd(&cnt, ok);
    __syncthreads();
    if (threadIdx.x == 0) *flag = (cnt > 2048) ? 1 : 0;
}

// ---------- convert raw (fp32 or bf16 per flag) -> canonical bf16 ----------
__global__ __launch_bounds__(256) void convert_to_bf16(
    const void* __restrict__ in, bf16* __restrict__ out, long n,
    const int* __restrict__ flag)
{
    long i = ((long)blockIdx.x * 256 + threadIdx.x) * 8;
    if (i >= n) return;
    bf16 o[8];
    if (*flag) {
        const float* p = (const float*)in + i;
        float4 a = *(const float4*)p;
        float4 b = *(const float4*)(p + 4);
        o[0] = __float2bfloat16(a.x); o[1] = __float2bfloat16(a.y);
        o[2] = __float2bfloat16(a.z); o[3] = __float2bfloat16(a.w);
        o[4] = __float2bfloat16(b.x); o[5] = __float2bfloat16(b.y);
        o[6] = __float2bfloat16(b.z); o[7] = __float2bfloat16(b.w);
    } else {
        *(float4*)o = *(const float4*)((const bf16*)in + i);
    }
    *(float4*)&out[i] = *(float4*)o;
}

// ---------- emit canonical bf16 -> d_out in flag dtype (fallback tiers) ----
__global__ __launch_bounds__(256) void emit_out(
    const bf16* __restrict__ in, void* __restrict__ out, long n,
    const int* __restrict__ flag)
{
    long i = ((long)blockIdx.x * 256 + threadIdx.x) * 8;
    if (i >= n) return;
    bf16 v[8];
    *(float4*)v = *(const float4*)&in[i];
    if (*flag) {
        float* o = (float*)out + i;
        float4 a, b;
        a.x = __bfloat162float(v[0]); a.y = __bfloat162float(v[1]);
        a.z = __bfloat162float(v[2]); a.w = __bfloat162float(v[3]);
        b.x = __bfloat162float(v[4]); b.y = __bfloat162float(v[5]);
        b.z = __bfloat162float(v[6]); b.w = __bfloat162float(v[7]);
        *(float4*)o = a;
        *(float4*)(o + 4) = b;
    } else {
        *(float4*)((bf16*)out + i) = *(float4*)v;
    }
}

// ---------- transpose raw-dtype input -> bf16 output ----------
__global__ __launch_bounds__(256) void transpose_any(
    const void* __restrict__ inv, bf16* __restrict__ out,
    int ldin, int ldout, const int* __restrict__ flag)
{
    __shared__ bf16 tile[64][80];
    const int fp32 = *flag;
    const int c0 = blockIdx.x * 64;
    const int r0 = blockIdx.y * 64;
    const int tid = threadIdx.x;
#pragma unroll
    for (int it = 0; it < 2; ++it) {
        int ch = tid + it * 256;
        int r = ch >> 3, c = (ch & 7) * 8;
        long eidx = (long)(r0 + r) * ldin + (c0 + c);
        if (fp32) {
            const float* p = (const float*)inv + eidx;
            float4 a = *(const float4*)p;
            float4 b = *(const float4*)(p + 4);
            bf16 o[8];
            o[0] = __float2bfloat16(a.x); o[1] = __float2bfloat16(a.y);
            o[2] = __float2bfloat16(a.z); o[3] = __float2bfloat16(a.w);
            o[4] = __float2bfloat16(b.x); o[5] = __float2bfloat16(b.y);
            o[6] = __float2bfloat16(b.z); o[7] = __float2bfloat16(b.w);
            *(float4*)&tile[r][c] = *(float4*)o;
        } else {
            *(float4*)&tile[r][c] = *(const float4*)((const bf16*)inv + eidx);
        }
    }
    __syncthreads();
#pragma unroll
    for (int it = 0; it < 2; ++it) {
        int ch = tid + it * 256;
        int oc = ch >> 3, rb = (ch & 7) * 8;
        bf16 tmp[8];
#pragma unroll
        for (int i = 0; i < 8; ++i) tmp[i] = tile[rb + i][oc];
        *(float4*)&out[(long)(c0 + oc) * ldout + r0 + rb] = *(float4*)tmp;
    }
}

// ---------- pure-bf16 transpose (fallback tiers) ----------
__global__ __launch_bounds__(256) void transpose_bf16(
    const bf16* __restrict__ in, bf16* __restrict__ out,
    int ldin, int ldout,
    int nz1, long in_z1, long out_z1, long in_z2, long out_z2)
{
    __shared__ bf16 tile[64][80];
    const int z = blockIdx.z;
    const int z1 = z % nz1, z2 = z / nz1;
    in  += (long)z1 * in_z1 + (long)z2 * in_z2;
    out += (long)z1 * out_z1 + (long)z2 * out_z2;
    const int c0 = blockIdx.x * 64;
    const int r0 = blockIdx.y * 64;
    const int tid = threadIdx.x;
#pragma unroll
    for (int it = 0; it < 2; ++it) {
        int ch = tid + it * 256;
        int r = ch >> 3, c = (ch & 7) * 8;
        *(float4*)&tile[r][c] = *(const float4*)&in[(long)(r0 + r) * ldin + c0 + c];
    }
    __syncthreads();
#pragma unroll
    for (int it = 0; it < 2; ++it) {
        int ch = tid + it * 256;
        int oc = ch >> 3, rb = (ch & 7) * 8;
        bf16 tmp[8];
#pragma unroll
        for (int i = 0; i < 8; ++i) tmp[i] = tile[rb + i][oc];
        *(float4*)&out[(long)(c0 + oc) * ldout + r0 + rb] = *(float4*)tmp;
    }
}

// =====================================================================
// 256x256-tile 8-wave 8-phase GEMM. C = A * Bt^T.
// MODE 1 (QK, swapped operands A=K,B=Q): S[q][s] = exp(acc), written as
//   8B packets (lane holds 4 consecutive s of one q-row); nontemporal.
// MODE 4 (QKV): Q|K part via 4x4 shuffle transpose -> 8B row stores;
//   V part written transposed to Vt (8B granule, unchanged).
// SWZ 1: head-per-XCD for grid (8,8,8).  SWZ 2: 6-ntile column chunks per
//   XCD for grid (48,8,1).  (T1; write bursts otherwise thrash L2.)
// =====================================================================
template <int MODE, int SWZ>
__global__ __launch_bounds__(512, 2) void gemm256(
    const bf16* __restrict__ A, const bf16* __restrict__ Bt,
    bf16* __restrict__ C, const bf16* __restrict__ bias,
    int lda, int ldb, int ldc,
    long az, long bz, long cz, int K, float scale, int qcols,
    bf16* __restrict__ Vt, int vcol0)
{
    __shared__ bf16 AsL[2][2][256 * 32];
    __shared__ bf16 BsL[2][2][256 * 32];

    const int tid  = threadIdx.x;
    const int lane = tid & 63;
    const int wave = tid >> 6;
    const int wr = wave >> 2;        // 0..1  row half of C tile
    const int wc = wave & 3;         // 0..3  col quarter of C tile
    const int lm = lane & 15;
    const int cl = lane >> 4;        // fragment k-chunk 0..3

    int bxx = blockIdx.x, byy = blockIdx.y, bzz = blockIdx.z;
    if constexpr (SWZ == 1) {        // grid (8,8,8): head z = XCD
        int flat = bxx + (byy << 3) + (bzz << 6);
        int xcd = flat & 7, idx = flat >> 3;
        bzz = xcd; bxx = idx & 7; byy = idx >> 3;
    } else if constexpr (SWZ == 2) { // grid (48,8,1): 6 n-tiles per XCD
        int flat = bxx + byy * 48;
        int xcd = flat & 7, idx = flat >> 3;
        bxx = xcd * 6 + idx % 6; byy = idx / 6; bzz = 0;
    }
    const long zz = bzz;
    A  += zz * az;
    Bt += zz * bz;
    C  += zz * cz;
    const int m0 = byy * 256;
    const int n0 = bxx * 256;

    // per-lane swizzled ds_read offsets within a [256][32] k-half block
    int offA[8], offB[4];
#pragma unroll
    for (int i = 0; i < 8; ++i) {
        int row = wr * 128 + i * 16 + lm;
        offA[i] = row * 32 + ((cl ^ ((row >> 1) & 3)) << 3);
    }
#pragma unroll
    for (int j = 0; j < 4; ++j) {
        int row = wc * 64 + j * 16 + lm;
        offB[j] = row * 32 + ((cl ^ ((row >> 1) & 3)) << 3);
    }

    const int sr = lane >> 2;        // staging row-in-16
    const int sc = lane & 3;         // staging chunk
    const int NT = K >> 6;           // 64-wide K tiles (NT even)

    floatx4 acc[8][4];
#pragma unroll
    for (int i = 0; i < 8; ++i)
#pragma unroll
        for (int j = 0; j < 4; ++j)
            acc[i][j] = (floatx4){0.f, 0.f, 0.f, 0.f};

    // stage one (operand, khalf) unit of tile t: 2 x global_load_lds
    auto stageU = [&](int which, int t, int kh) {
        if (t >= NT) return;
        const bf16* G = which ? Bt : A;
        const int ldg  = which ? ldb : lda;
        const int g0   = which ? n0 : m0;
        bf16* lb = which ? &BsL[t & 1][kh][0] : &AsL[t & 1][kh][0];
        const int kcol = t * 64 + kh * 32;
#pragma unroll
        for (int ii = 0; ii < 2; ++ii) {
            int row = ii * 128 + wave * 16 + sr;
            int cg  = sc ^ ((row >> 1) & 3);   // pre-swizzled global chunk
            gload_lds16(G + (long)(g0 + row) * ldg + kcol + cg * 8,
                        lb + row * 32 + sc * 8);
        }
    };

    bf16x8 af[8], bfv[2];
    auto dsA = [&](int b, int kh) {
        const bf16* p = &AsL[b][kh][0];
#pragma unroll
        for (int i = 0; i < 8; ++i) af[i] = *(const bf16x8*)(p + offA[i]);
    };
    auto dsB = [&](int b, int kh, int nh) {
        const bf16* p = &BsL[b][kh][0];
        bfv[0] = *(const bf16x8*)(p + offB[nh * 2]);
        bfv[1] = *(const bf16x8*)(p + offB[nh * 2 + 1]);
    };
    auto mfmaQ = [&](int nh) {
        __builtin_amdgcn_s_setprio(1);
#pragma unroll
        for (int i = 0; i < 8; ++i) {
            acc[i][nh * 2] = __builtin_amdgcn_mfma_f32_16x16x32_bf16(
                af[i], bfv[0], acc[i][nh * 2], 0, 0, 0);
            acc[i][nh * 2 + 1] = __builtin_amdgcn_mfma_f32_16x16x32_bf16(
                af[i], bfv[1], acc[i][nh * 2 + 1], 0, 0, 0);
        }
        __builtin_amdgcn_s_setprio(0);
    };

#define BAR    __builtin_amdgcn_s_barrier()
#define SBZ    __builtin_amdgcn_sched_barrier(0)
#define LGKM0  do { asm volatile("s_waitcnt lgkmcnt(0)" ::: "memory"); SBZ; } while (0)
#define VM(n)  do { asm volatile("s_waitcnt vmcnt(" #n ")" ::: "memory"); SBZ; } while (0)

    // ---- prologue: tile0 (all), tile1 k0 ----
    stageU(0, 0, 0); stageU(1, 0, 0); stageU(0, 0, 1); stageU(1, 0, 1);
    stageU(0, 1, 0); stageU(1, 1, 0);
    VM(4);
    BAR;

    for (int t0 = 0; t0 < NT; t0 += 2) {
        const bool last = (t0 + 2 >= NT);
        dsA(0, 0); dsB(0, 0, 0); stageU(0, t0 + 1, 1);
        BAR; LGKM0; mfmaQ(0); BAR;
        dsB(0, 0, 1); stageU(1, t0 + 1, 1);
        BAR; LGKM0; mfmaQ(1); BAR;
        dsA(0, 1); dsB(0, 1, 0); stageU(0, t0 + 2, 0);
        BAR; LGKM0; mfmaQ(0); BAR;
        dsB(0, 1, 1); stageU(1, t0 + 2, 0);
        BAR; LGKM0; mfmaQ(1);
        if (last) { VM(0); } else { VM(4); }
        BAR;
        dsA(1, 0); dsB(1, 0, 0); stageU(0, t0 + 2, 1);
        BAR; LGKM0; mfmaQ(0); BAR;
        dsB(1, 0, 1); stageU(1, t0 + 2, 1);
        BAR; LGKM0; mfmaQ(1); BAR;
        dsA(1, 1); dsB(1, 1, 0); stageU(0, t0 + 3, 0);
        BAR; LGKM0; mfmaQ(0); BAR;
        dsB(1, 1, 1); stageU(1, t0 + 3, 0);
        BAR; LGKM0; mfmaQ(1);
        if (!last) { VM(4); }
        BAR;
    }
#undef BAR
#undef SBZ
#undef LGKM0
#undef VM

    // ---- epilogue ----
    const int cr = (lane >> 4) * 4;
    if constexpr (MODE == 1) {
        // swapped operands: acc(row=s, col=q). Store S[q][s] = exp(acc):
        // lane holds 4 consecutive s -> 8B packet; nontemporal (S is 67MB,
        // written once, consumed only by the PV kernel).
#pragma unroll
        for (int j = 0; j < 4; ++j) {
            long q = n0 + wc * 64 + j * 16 + lm;
            bf16* Cr = C + q * ldc + m0 + wr * 128;
#pragma unroll
            for (int i = 0; i < 8; ++i) {
                bf16 pk[4];
#pragma unroll
                for (int r = 0; r < 4; ++r)
                    pk[r] = __float2bfloat16(__expf(acc[i][j][r]));
                __builtin_nontemporal_store(*(const uint64_t*)pk,
                                            (uint64_t*)&Cr[i * 16 + cr]);
            }
        }
    } else {   // MODE 4
        if (n0 >= vcol0) {
            // V block: write transposed, packed 4 consecutive t per 8B store
#pragma unroll
            for (int j = 0; j < 4; ++j) {
                int col = n0 + wc * 64 + j * 16 + lm;
                float bv = __bfloat162float(bias[col]);
                int eg = col - vcol0;
                bf16* vt = Vt + ((long)(eg >> 9) * 512 + (eg & 511)) * 2048;
#pragma unroll
                for (int i = 0; i < 8; ++i) {
                    int t0v = m0 + wr * 128 + i * 16 + cr;
                    bf16 pk[4];
#pragma unroll
                    for (int r = 0; r < 4; ++r)
                        pk[r] = __float2bfloat16(acc[i][j][r] + bv);
                    *(uint64_t*)&vt[t0v] = *(const uint64_t*)pk;
                }
            }
        } else {
            // Q|K: bias+scale in original (col-per-lane) layout, then 4x4
            // shuffle transpose (lanes l4 x regs) -> lane holds 4 consecutive
            // channels of one row -> 8B stores.
            const int l4 = lane & 3;
            float bvj[4], scj[4];
#pragma unroll
            for (int j = 0; j < 4; ++j) {
                int col = n0 + wc * 64 + j * 16 + lm;
                bvj[j] = __bfloat162float(bias[col]);
                scj[j] = (col < qcols) ? scale : 1.0f;
            }
#pragma unroll
            for (int i = 0; i < 8; ++i) {
                int row = m0 + wr * 128 + i * 16 + cr + l4;
                bf16* Cr = C + (long)row * ldc + n0 + wc * 64 + (lm & ~3);
#pragma unroll
                for (int j = 0; j < 4; ++j) {
                    float x0 = (acc[i][j][0] + bvj[j]) * scj[j];
                    float x1 = (acc[i][j][1] + bvj[j]) * scj[j];
                    float x2 = (acc[i][j][2] + bvj[j]) * scj[j];
                    float x3 = (acc[i][j][3] + bvj[j]) * scj[j];
                    // swap (lane bit0, reg bit0)
                    float u = __shfl_xor((l4 & 1) ? x0 : x1, 1);
                    float v = __shfl_xor((l4 & 1) ? x2 : x3, 1);
                    if (l4 & 1) { x0 = u; x2 = v; } else { x1 = u; x3 = v; }
                    // swap (lane bit1, reg bit1)
                    u = __shfl_xor((l4 & 2) ? x0 : x2, 2);
                    v = __shfl_xor((l4 & 2) ? x1 : x3, 2);
                    if (l4 & 2) { x0 = u; x1 = v; } else { x2 = u; x3 = v; }
                    bf16 pk[4];
                    pk[0] = __float2bfloat16(x0); pk[1] = __float2bfloat16(x1);
                    pk[2] = __float2bfloat16(x2); pk[3] = __float2bfloat16(x3);
                    *(uint64_t*)&Cr[j * 16] = *(const uint64_t*)pk;
                }
            }
        }
    }
}

// ---------- GEMM (bf16 in/out, fp32 acc), templated epilogue -------------
// MODE 0: C = (acc + bias) * (col<qcols ? scale : 1)
// MODE 1: C = exp(acc)
// MODE 2: C += acc   (tier-D accumulate)
// MODE 3: swapped-operand PV: A=Vt (rows=ch), Bt=S (rows=t);
//         C[t][ch] = acc / L[t], L = col-sum of S via ones-MFMA; 8B stores.
// MODE 4: QKV projection with fused V-transpose
// SWZ 3: head-per-XCD remap for grid (16,4,8) (PV).
template <int MODE, bool SWAP = false, int SWZ = 0>
__global__ __launch_bounds__(256) void gemm_bt(
    const bf16* __restrict__ A, const bf16* __restrict__ Bt,
    bf16* __restrict__ C, const bf16* __restrict__ bias,
    int lda, int ldb, int ldc,
    long az, long bz, long cz, int K, float scale, int qcols,
    bf16* __restrict__ Vt, int vcol0)
{
    __shared__ bf16 As[128 * 64];
    __shared__ bf16 Bs[128 * 64];

    const int tid  = threadIdx.x;
    const int lane = tid & 63;
    const int wave = tid >> 6;
    const int wx = wave & 1;
    const int wy = wave >> 1;

    int bxx = blockIdx.x, byy = blockIdx.y, bzz = blockIdx.z;
    if constexpr (SWZ == 3) {        // grid (16,4,8): head z = XCD; y fast
        int flat = bxx + (byy << 4) + (bzz << 6);
        int xcd = flat & 7, idx = flat >> 3;
        bzz = xcd; byy = idx & 3; bxx = idx >> 2;
    }
    const long zz = bzz;
    A  += zz * az;
    Bt += zz * bz;
    C  += zz * cz;
    const int bm = SWAP ? bxx : byy;
    const int bn = SWAP ? byy : bxx;
    const int m0 = bm * 128;
    const int n0 = bn * 128;

    const int lm = lane & 15;
    const int kq = (lane >> 4) * 8;

    floatx4 acc[4][4];
#pragma unroll
    for (int i = 0; i < 4; ++i)
#pragma unroll
        for (int j = 0; j < 4; ++j)
            acc[i][j] = (floatx4){0.f, 0.f, 0.f, 0.f};

    floatx4 accOnes[4];
    bf16x8 ones;
    if constexpr (MODE == 3) {
#pragma unroll
        for (int i = 0; i < 4; ++i) accOnes[i] = (floatx4){0.f, 0.f, 0.f, 0.f};
#pragma unroll
        for (int k = 0; k < 8; ++k) ones[k] = (__bf16)1.0f;
    }

    for (int kt = 0; kt < K; kt += 64) {
        __syncthreads();
#pragma unroll
        for (int it = 0; it < 4; ++it) {
            int ch = tid + it * 256;
            int r = ch >> 3;
            int c = (ch & 7) * 8;
            gload_lds16(A  + (long)(m0 + r) * lda + (kt + c), &As[ch * 8]);
            gload_lds16(Bt + (long)(n0 + r) * ldb + (kt + c), &Bs[ch * 8]);
        }
        __syncthreads();
#pragma unroll
        for (int kk = 0; kk < 64; kk += 32) {
            bf16x8 af[4], bfv[4];
#pragma unroll
            for (int i = 0; i < 4; ++i)
                af[i] = *(const bf16x8*)&As[(wy * 64 + i * 16 + lm) * 64 + kk + kq];
#pragma unroll
            for (int j = 0; j < 4; ++j)
                bfv[j] = *(const bf16x8*)&Bs[(wx * 64 + j * 16 + lm) * 64 + kk + kq];
            if constexpr (MODE == 3) {
#pragma unroll
                for (int j = 0; j < 4; ++j)
                    accOnes[j] = __builtin_amdgcn_mfma_f32_16x16x32_bf16(
                        ones, bfv[j], accOnes[j], 0, 0, 0);
            }
#pragma unroll
            for (int i = 0; i < 4; ++i)
#pragma unroll
                for (int j = 0; j < 4; ++j)
                    acc[i][j] = __builtin_amdgcn_mfma_f32_16x16x32_bf16(
                        af[i], bfv[j], acc[i][j], 0, 0, 0);
        }
    }

    const int cr = (lane >> 4) * 4;
    if constexpr (MODE == 1) {
#pragma unroll
        for (int j = 0; j < 4; ++j) {
            int col = n0 + wx * 64 + j * 16 + lm;
#pragma unroll
            for (int i = 0; i < 4; ++i)
#pragma unroll
                for (int r = 0; r < 4; ++r) {
                    int row = m0 + wy * 64 + i * 16 + cr + r;
                    C[(long)row * ldc + col] = __float2bfloat16(__expf(acc[i][j][r]));
                }
        }
    } else if constexpr (MODE == 3) {
        // swapped: rows=ch, cols=t; divide by L[t]; 8B stores over ch
#pragma unroll
        for (int j = 0; j < 4; ++j) {
            int tcol = n0 + wx * 64 + j * 16 + lm;
            float inv = 1.0f / accOnes[j][0];
            bf16* Cr = C + (long)tcol * ldc + m0 + wy * 64;
#pragma unroll
            for (int i = 0; i < 4; ++i) {
                bf16 pk[4];
#pragma unroll
                for (int r = 0; r < 4; ++r)
                    pk[r] = __float2bfloat16(acc[i][j][r] * inv);
                *(uint64_t*)&Cr[i * 16 + cr] = *(const uint64_t*)pk;
            }
        }
    } else if constexpr (MODE == 4) {
        if (n0 >= vcol0) {
#pragma unroll
            for (int j = 0; j < 4; ++j) {
                int col = n0 + wx * 64 + j * 16 + lm;
                float bv = __bfloat162float(bias[col]);
                int eg = col - vcol0;
                bf16* vt = Vt + ((long)(eg >> 9) * 512 + (eg & 511)) * 2048;
#pragma unroll
                for (int i = 0; i < 4; ++i) {
                    int t0 = m0 + wy * 64 + i * 16 + cr;
                    bf16 pk[4];
#pragma unroll
                    for (int r = 0; r < 4; ++r)
                        pk[r] = __float2bfloat16(acc[i][j][r] + bv);
                    *(uint64_t*)&vt[t0] = *(const uint64_t*)pk;
                }
            }
        } else {
#pragma unroll
            for (int j = 0; j < 4; ++j) {
                int col = n0 + wx * 64 + j * 16 + lm;
                float bv = __bfloat162float(bias[col]);
                float sc = (col < qcols) ? scale : 1.0f;
#pragma unroll
                for (int i = 0; i < 4; ++i)
#pragma unroll
                    for (int r = 0; r < 4; ++r) {
                        int row = m0 + wy * 64 + i * 16 + cr + r;
                        C[(long)row * ldc + col] =
                            __float2bfloat16((acc[i][j][r] + bv) * sc);
                    }
            }
        }
    } else {
#pragma unroll
        for (int j = 0; j < 4; ++j) {
            int col = n0 + wx * 64 + j * 16 + lm;
            float bv = (MODE == 0 && bias) ? __bfloat162float(bias[col]) : 0.f;
            float sc = (col < qcols) ? scale : 1.0f;
#pragma unroll
            for (int i = 0; i < 4; ++i) {
#pragma unroll
                for (int r = 0; r < 4; ++r) {
                    int row = m0 + wy * 64 + i * 16 + cr + r;
                    long idx = (long)row * ldc + col;
                    float v;
                    if (MODE == 2) v = acc[i][j][r] + __bfloat162float(C[idx]);
                    else           v = (acc[i][j][r] + bv) * sc;
                    C[idx] = __float2bfloat16(v);
                }
            }
        }
    }
}

// ---------- split-K GEMM, bf16 partials ------------------
// SWZ 9 (tier B2 out-proj, grid (64,4,2), swapped operands A=WoT, Bt=Oatt):
//   chunked XCD remap (one W-panel + one sk-half per XCD) and 8B
//   stores P[t][ch] (same final layout as the old path -> reduce unchanged).
template <bool SWAP = false, int SWZ = 0>
__global__ __launch_bounds__(256) void gemm_bt_splitk(
    const bf16* __restrict__ A, const bf16* __restrict__ Bt,
    bf16* __restrict__ P, int lda, int ldb, int ldp,
    long az, long bz, long pz, long skStride, int nsk, int Kc)
{
    __shared__ bf16 As[128 * 64];
    __shared__ bf16 Bs[128 * 64];

    const int tid  = threadIdx.x;
    const int lane = tid & 63;
    const int wave = tid >> 6;
    const int wx = wave & 1;
    const int wy = wave >> 1;

    int bxx = blockIdx.x, byy = blockIdx.y, bzz = blockIdx.z;
    if constexpr (SWZ == 9) {        // grid (64,4,2) chunked remap
        int flat = bxx + (byy << 6) + (bzz << 8);
        int nf = (flat & 7) * 64 + (flat >> 3);
        bxx = nf & 63; byy = (nf >> 6) & 3; bzz = nf >> 8;
    }
    const int zz = bzz;
    const int ks = zz % nsk;
    const int zh = zz / nsk;
    A  += (long)zh * az;
    Bt += (long)zh * bz;
    bf16* Pz = P + (long)zh * pz + (long)ks * skStride;
    const int bm = SWAP ? bxx : byy;
    const int bn = SWAP ? byy : bxx;
    const int m0 = bm * 128;
    const int n0 = bn * 128;
    const int k0 = ks * Kc;

    const int lm = lane & 15;
    const int kq = (lane >> 4) * 8;

    floatx4 acc[4][4];
#pragma unroll
    for (int i = 0; i < 4; ++i)
#pragma unroll
        for (int j = 0; j < 4; ++j)
            acc[i][j] = (floatx4){0.f, 0.f, 0.f, 0.f};

    for (int kt = k0; kt < k0 + Kc; kt += 64) {
        __syncthreads();
#pragma unroll
        for (int it = 0; it < 4; ++it) {
            int ch = tid + it * 256;
            int r = ch >> 3;
            int c = (ch & 7) * 8;
            gload_lds16(A  + (long)(m0 + r) * lda + (kt + c), &As[ch * 8]);
            gload_lds16(Bt + (long)(n0 + r) * ldb + (kt + c), &Bs[ch * 8]);
        }
        __syncthreads();
#pragma unroll
        for (int kk = 0; kk < 64; kk += 32) {
            bf16x8 af[4], bfv[4];
#pragma unroll
            for (int i = 0; i < 4; ++i)
                af[i] = *(const bf16x8*)&As[(wy * 64 + i * 16 + lm) * 64 + kk + kq];
#pragma unroll
            for (int j = 0; j < 4; ++j)
                bfv[j] = *(const bf16x8*)&Bs[(wx * 64 + j * 16 + lm) * 64 + kk + kq];
#pragma unroll
            for (int i = 0; i < 4; ++i)
#pragma unroll
                for (int j = 0; j < 4; ++j)
                    acc[i][j] = __builtin_amdgcn_mfma_f32_16x16x32_bf16(
                        af[i], bfv[j], acc[i][j], 0, 0, 0);
        }
    }

    const int cr = (lane >> 4) * 4;
    if constexpr (SWZ == 9) {
        // swapped operands: rows=out-ch, cols=t. Store P[t*ldp + ch] 8B.
#pragma unroll
        for (int j = 0; j < 4; ++j) {
            int tcol = n0 + wx * 64 + j * 16 + lm;
            bf16* Pr = Pz + (long)tcol * ldp + m0 + wy * 64;
#pragma unroll
            for (int i = 0; i < 4; ++i) {
                bf16 pk[4];
#pragma unroll
                for (int r = 0; r < 4; ++r)
                    pk[r] = __float2bfloat16(acc[i][j][r]);
                *(uint64_t*)&Pr[i * 16 + cr] = *(const uint64_t*)pk;
            }
        }
    } else {
#pragma unroll
        for (int j = 0; j < 4; ++j) {
            int col = n0 + wx * 64 + j * 16 + lm;
#pragma unroll
            for (int i = 0; i < 4; ++i)
#pragma unroll
                for (int r = 0; r < 4; ++r) {
                    int row = m0 + wy * 64 + i * 16 + cr + r;
                    Pz[(long)row * ldp + col] = __float2bfloat16(acc[i][j][r]);
                }
        }
    }
}

// ---------- reduce 2 bf16 split-K partials + bias -> d_out in flag dtype ----
__global__ __launch_bounds__(256) void reduce_emit(
    const bf16* __restrict__ P, const bf16* __restrict__ bias,
    void* __restrict__ out, long MN, int N,
    const int* __restrict__ flag)
{
    long i = ((long)blockIdx.x * 256 + threadIdx.x) * 8;
    if (i >= MN) return;
    bf16 bb[8], a[8], b[8];
    *(float4*)bb = *(const float4*)&bias[i & (N - 1)];
    *(float4*)a  = *(const float4*)&P[i];
    *(float4*)b  = *(const float4*)&P[MN + i];
    float s[8];
#pragma unroll
    for (int k = 0; k < 8; ++k)
        s[k] = __bfloat162float(bb[k]) + __bfloat162float(a[k]) + __bfloat162float(b[k]);
    if (*flag) {
        float* o = (float*)out + i;
        float4 lo = {s[0], s[1], s[2], s[3]};
        float4 hi = {s[4], s[5], s[6], s[7]};
        *(float4*)o = lo;
        *(float4*)(o + 4) = hi;
    } else {
        bf16 o[8];
#pragma unroll
        for (int k = 0; k < 8; ++k) o[k] = __float2bfloat16(s[k]);
        *(float4*)&((bf16*)out)[i] = *(float4*)o;
    }
}

// ---------- reduce bf16 split-K partials + bias -> bf16 (fallback) ----------
__global__ __launch_bounds__(256) void reduce_splitk(
    const bf16* __restrict__ P, const bf16* __restrict__ bias,
    bf16* __restrict__ Out, long MN, int N, int SK)
{
    long i = ((long)blockIdx.x * 256 + threadIdx.x) * 8;
    if (i >= MN) return;
    float s[8];
    if (bias) {
        bf16 bb[8];
        *(float4*)bb = *(const float4*)&bias[i & (N - 1)];
#pragma unroll
        for (int k = 0; k < 8; ++k) s[k] = __bfloat162float(bb[k]);
    } else {
#pragma unroll
        for (int k = 0; k < 8; ++k) s[k] = 0.f;
    }
    for (int z = 0; z < SK; ++z) {
        bf16 a[8];
        *(float4*)a = *(const float4*)&P[(long)z * MN + i];
#pragma unroll
        for (int k = 0; k < 8; ++k) s[k] += __bfloat162float(a[k]);
    }
    bf16 o[8];
#pragma unroll
    for (int k = 0; k < 8; ++k) o[k] = __float2bfloat16(s[k]);
    *(float4*)&Out[i] = *(float4*)o;
}

// ---------- in-place softmax over rows of 2048 bf16 (fallback tiers) -----
__global__ __launch_bounds__(256) void softmax_rows2048(bf16* __restrict__ S)
{
    __shared__ float red[8];
    const long row = blockIdx.x;
    bf16* p = S + row * 2048;
    const int tid = threadIdx.x;
    float4 raw = *(const float4*)&p[tid * 8];
    bf16 vb[8];
    *(float4*)vb = raw;
    float v[8];
#pragma unroll
    for (int i = 0; i < 8; ++i) v[i] = __bfloat162float(vb[i]);
    float m = v[0];
#pragma unroll
    for (int i = 1; i < 8; ++i) m = fmaxf(m, v[i]);
#pragma unroll
    for (int o = 32; o > 0; o >>= 1) m = fmaxf(m, __shfl_xor(m, o));
    if ((tid & 63) == 0) red[tid >> 6] = m;
    __syncthreads();
    m = fmaxf(fmaxf(red[0], red[1]), fmaxf(red[2], red[3]));
    float s = 0.f;
#pragma unroll
    for (int i = 0; i < 8; ++i) { v[i] = __expf(v[i] - m); s += v[i]; }
#pragma unroll
    for (int o = 32; o > 0; o >>= 1) s += __shfl_xor(s, o);
    if ((tid & 63) == 0) red[4 + (tid >> 6)] = s;
    __syncthreads();
    s = (red[4] + red[5]) + (red[6] + red[7]);
    float inv = 1.f / s;
#pragma unroll
    for (int i = 0; i < 8; ++i) vb[i] = __float2bfloat16(v[i] * inv);
    *(float4*)&p[tid * 8] = *(float4*)vb;
}

extern "C" void kernel_launch(void* const* d_in, const int* in_sizes, int n_in,
                              void* d_out, int out_size, void* d_ws, size_t ws_size,
                              hipStream_t stream)
{
    const int Bb = 4, T = 2048, E = 512, H = 8;
    const int HE = H * E;            // 4096
    const int N3 = 3 * HE;           // 12288
    const int N2 = 2 * HE;           // 8192 (Q|K row width)
    const int M  = Bb * T;           // 8192
    const long NX = (long)M * E;     // 4,194,304

    // ---- size-signature input assignment (order-robust) ----
    const void* xr = nullptr;
    const void* Wr[4] = {nullptr, nullptr, nullptr, nullptr};
    const void* br[3] = {nullptr, nullptr, nullptr};
    const void* bor = nullptr;
    int nw = 0, nb = 0;
    for (int i = 0; i < n_in; ++i) {
        int s = in_sizes[i];
        if      (s == (int)NX)      xr = d_in[i];
        else if (s == E * HE)       { if (nw < 4) Wr[nw++] = d_in[i]; }
        else if (s == HE)           { if (nb < 3) br[nb++] = d_in[i]; }
        else if (s == E)            bor = d_in[i];
    }
    if (!xr || nw < 4 || nb < 3 || !bor) {
        xr = d_in[0]; Wr[0] = d_in[1]; br[0] = d_in[2]; Wr[1] = d_in[3];
        br[1] = d_in[4]; Wr[2] = d_in[5]; br[2] = d_in[6]; Wr[3] = d_in[7];
        bor = d_in[8];
    }

    const float qscale = 0.04419417382415922f;  // 1/sqrt(512)
    const int   QC = 1 << 30;
    dim3 blk(256);

    // ---- workspace layout (bf16 elements) ----
    bf16* pool = (bf16*)d_ws;
    int*  flag = (int*)(void*)pool;
    bf16* xc   = pool + 8;
    bf16* bqc  = xc  + NX;
    bf16* bkc  = bqc + HE;
    bf16* bvc  = bkc + HE;
    bf16* boc  = bvc + HE;
    bf16* WqT  = boc + E;
    const size_t w2m = (size_t)E * HE;
    bf16* WkT  = WqT + w2m;
    bf16* WvT  = WkT + w2m;
    bf16* WoT  = WvT + w2m;
    bf16* Ofin = WoT + w2m;
    bf16* p0   = Ofin + NX;

    const size_t wsE    = ws_size / sizeof(bf16);
    const size_t fixedE = (size_t)(p0 - pool);
    const size_t wQK   = (size_t)T * N2;
    const size_t wQKV  = (size_t)T * N3;
    const size_t wBat  = (size_t)T * HE;
    const size_t wHd   = (size_t)T * E;
    const size_t sAll  = (size_t)H * T * T;
    const size_t sOne  = (size_t)T * T;
    const size_t wBig  = (size_t)M * HE;
    const size_t needB2 = fixedE + wQK + wBat + sAll + wBig;
    const size_t needB  = fixedE + wQKV + 2 * wBat + sAll;
    const size_t needC  = fixedE + 5 * wBat + sOne;
    const size_t needD  = fixedE + 5 * wHd  + sOne;
    if (wsE < needD) return;

    // ---- stage 0: dtype probe + canonicalize ----
    probe_dtype<<<dim3(1), blk, 0, stream>>>((const float*)xr, flag);
    convert_to_bf16<<<dim3((unsigned)((NX / 8 + 255) / 256)), blk, 0, stream>>>(
        xr, xc, NX, flag);
    convert_to_bf16<<<dim3(2), blk, 0, stream>>>(br[0], bqc, HE, flag);
    convert_to_bf16<<<dim3(2), blk, 0, stream>>>(br[1], bkc, HE, flag);
    convert_to_bf16<<<dim3(2), blk, 0, stream>>>(br[2], bvc, HE, flag);
    convert_to_bf16<<<dim3(1), blk, 0, stream>>>(bor, boc, E, flag);
    transpose_any<<<dim3(HE / 64, E / 64, 1), blk, 0, stream>>>(Wr[0], WqT, HE, E, flag);
    transpose_any<<<dim3(HE / 64, E / 64, 1), blk, 0, stream>>>(Wr[1], WkT, HE, E, flag);
    transpose_any<<<dim3(HE / 64, E / 64, 1), blk, 0, stream>>>(Wr[2], WvT, HE, E, flag);
    transpose_any<<<dim3(E / 64, HE / 64, 1), blk, 0, stream>>>(Wr[3], WoT, E, HE, flag);

    if (wsE >= needB2) {
        // ---- Tier B2: 256² 8-phase QKV+QK (fixed stores + XCD swizzle);
        //      swapped-operand PV + out-proj with 8B stores ----
        bf16* QKb = p0;                  // [t, 8192] = Q|K; aliased for P later
        bf16* Vtb = QKb + wQK;           // [h,e,t]
        bf16* S   = Vtb + wBat;          // exp(scores) [h,t,s]
        bf16* Oatt = S + sAll;           // O_all [M, HE]

        for (int b = 0; b < Bb; ++b) {
            const bf16* xb = xc + (size_t)b * T * E;
            // merged QKV projection; V columns written transposed to Vtb
            gemm256<4, 2><<<dim3(N3 / 256, T / 256, 1), dim3(512), 0, stream>>>(
                xb, WqT, QKb, bqc, E, E, N2, 0, 0, 0, E, qscale, HE, Vtb, N2);
            // QK swapped (A=K, B=Q): S[q][s] = exp(QK^T), contiguous stores
            gemm256<1, 1><<<dim3(T / 256, T / 256, H), dim3(512), 0, stream>>>(
                QKb + HE, QKb, S, nullptr, N2, N2, T,
                (long)E, (long)E, (long)T * T, E, 1.f, QC, nullptr, 0);
            // PV swapped (A=Vt, B=S): O[t][ch] = (S V)/rowsum(S)
            gemm_bt<3, false, 3><<<dim3(T / 128, E / 128, H), blk, 0, stream>>>(
                Vtb, S, Oatt + (size_t)b * T * HE, nullptr, T, T, HE,
                (long)E * T, (long)T * T, (long)E, T, 1.f, QC, nullptr, 0);
        }
        // out-proj swapped (A=WoT, B=Oatt): split-K=2, chunked XCD remap
        gemm_bt_splitk<false, 9><<<dim3(M / 128, E / 128, 2), blk, 0, stream>>>(
            WoT, Oatt, QKb, HE, HE, E, 0, 0, 0, (long)M * E, 2, HE / 2);
        reduce_emit<<<dim3((unsigned)((NX / 8 + 255) / 256)), blk, 0, stream>>>(
            QKb, boc, d_out, NX, E, flag);
        return;
    }

    if (wsE >= needB) {
        // ---- Tier B fallback: softmax path ----
        bf16* QKVb = p0;
        bf16* Vtb  = QKVb + wQKV;
        bf16* Oatt = Vtb + wBat;
        bf16* S    = Oatt + wBat;

        for (int b = 0; b < Bb; ++b) {
            const bf16* xb = xc + (size_t)b * T * E;
            gemm_bt<0><<<dim3(N3 / 128, T / 128, 1), blk, 0, stream>>>(
                xb, WqT, QKVb, bqc, E, E, N3, 0, 0, 0, E, qscale, HE, nullptr, 0);
            transpose_bf16<<<dim3(E / 64, T / 64, H), blk, 0, stream>>>(
                QKVb + 2 * HE, Vtb, N3, T, H, (long)E, (long)E * T, 0, 0);
            gemm_bt<0><<<dim3(T / 128, T / 128, H), blk, 0, stream>>>(
                QKVb, QKVb + HE, S, nullptr, N3, N3, T,
                (long)E, (long)E, (long)T * T, E, 1.f, QC, nullptr, 0);
            softmax_rows2048<<<dim3(H * T, 1, 1), blk, 0, stream>>>(S);
            gemm_bt<0><<<dim3(E / 128, T / 128, H), blk, 0, stream>>>(
                S, Vtb, Oatt, nullptr, T, T, HE,
                (long)T * T, (long)E * T, (long)E, T, 1.f, QC, nullptr, 0);
            gemm_bt_splitk<false><<<dim3(E / 128, T / 128, 8), blk, 0, stream>>>(
                Oatt, WoT, (bf16*)S, HE, HE, E, 0, 0, 0, (long)T * E, 8, HE / 8);
            reduce_splitk<<<dim3((unsigned)(((long)T * E / 8 + 255) / 256)), blk, 0, stream>>>(
                (bf16*)S, boc, Ofin + (size_t)b * T * E, (long)T * E, E, 8);
        }
    } else if (wsE >= needC) {
        // ---- Tier C fallback ----
        bf16* Qb  = p0;
        bf16* Kb  = Qb  + wBat;
        bf16* Vb  = Kb  + wBat;
        bf16* Vtb = Vb  + wBat;
        bf16* Ob  = Vtb + wBat;
        bf16* S   = Ob  + wBat;

        for (int b = 0; b < Bb; ++b) {
            const bf16* xb = xc + (size_t)b * T * E;
            gemm_bt<0><<<dim3(HE / 128, T / 128, 1), blk, 0, stream>>>(
                xb, WqT, Qb, bqc, E, E, HE, 0, 0, 0, E, qscale, QC, nullptr, 0);
            gemm_bt<0><<<dim3(HE / 128, T / 128, 1), blk, 0, stream>>>(
                xb, WkT, Kb, bkc, E, E, HE, 0, 0, 0, E, 1.f, QC, nullptr, 0);
            gemm_bt<0><<<dim3(HE / 128, T / 128, 1), blk, 0, stream>>>(
                xb, WvT, Vb, bvc, E, E, HE, 0, 0, 0, E, 1.f, QC, nullptr, 0);
            transpose_bf16<<<dim3(E / 64, T / 64, H), blk, 0, stream>>>(
                Vb, Vtb, HE, T, H, (long)E, (long)E * T, 0, 0);
            for (int h = 0; h < H; ++h) {
                gemm_bt<0><<<dim3(T / 128, T / 128, 1), blk, 0, stream>>>(
                    Qb + (size_t)h * E, Kb + (size_t)h * E, S, nullptr,
                    HE, HE, T, 0, 0, 0, E, 1.f, QC, nullptr, 0);
                softmax_rows2048<<<dim3(T, 1, 1), blk, 0, stream>>>(S);
                gemm_bt<0><<<dim3(E / 128, T / 128, 1), blk, 0, stream>>>(
                    S, Vtb + (size_t)h * E * T, Ob + (size_t)h * E, nullptr,
                    T, T, HE, 0, 0, 0, T, 1.f, QC, nullptr, 0);
            }
            gemm_bt<0><<<dim3(E / 128, T / 128, 1), blk, 0, stream>>>(
                Ob, WoT, Ofin + (size_t)b * T * E, boc,
                HE, HE, E, 0, 0, 0, HE, 1.f, QC, nullptr, 0);
        }
    } else {
        // ---- Tier D fallback ----
        bf16* Qh  = p0;
        bf16* Kh  = Qh  + wHd;
        bf16* Vh  = Kh  + wHd;
        bf16* Vth = Vh  + wHd;
        bf16* Oh  = Vth + wHd;
        bf16* S   = Oh  + wHd;

        for (int b = 0; b < Bb; ++b) {
            const bf16* xb = xc + (size_t)b * T * E;
            bf16* outb = Ofin + (size_t)b * T * E;
            for (int h = 0; h < H; ++h) {
                const size_t hw = (size_t)h * E * E;
                gemm_bt<0><<<dim3(E / 128, T / 128, 1), blk, 0, stream>>>(
                    xb, WqT + hw, Qh, bqc + (size_t)h * E, E, E, E,
                    0, 0, 0, E, qscale, QC, nullptr, 0);
                gemm_bt<0><<<dim3(E / 128, T / 128, 1), blk, 0, stream>>>(
                    xb, WkT + hw, Kh, bkc + (size_t)h * E, E, E, E,
                    0, 0, 0, E, 1.f, QC, nullptr, 0);
                gemm_bt<0><<<dim3(E / 128, T / 128, 1), blk, 0, stream>>>(
                    xb, WvT + hw, Vh, bvc + (size_t)h * E, E, E, E,
                    0, 0, 0, E, 1.f, QC, nullptr, 0);
                transpose_bf16<<<dim3(E / 64, T / 64, 1), blk, 0, stream>>>(
                    Vh, Vth, E, T, 1, 0, 0, 0, 0);
                gemm_bt<0><<<dim3(T / 128, T / 128, 1), blk, 0, stream>>>(
                    Qh, Kh, S, nullptr, E, E, T, 0, 0, 0, E, 1.f, QC, nullptr, 0);
                softmax_rows2048<<<dim3(T, 1, 1), blk, 0, stream>>>(S);
                gemm_bt<0><<<dim3(E / 128, T / 128, 1), blk, 0, stream>>>(
                    S, Vth, Oh, nullptr, T, T, E, 0, 0, 0, T, 1.f, QC, nullptr, 0);
                if (h == 0)
                    gemm_bt<0><<<dim3(E / 128, T / 128, 1), blk, 0, stream>>>(
                        Oh, WoT, outb, boc, E, HE, E, 0, 0, 0, E, 1.f, QC, nullptr, 0);
                else
                    gemm_bt<2><<<dim3(E / 128, T / 128, 1), blk, 0, stream>>>(
                        Oh, WoT + (size_t)h * E, outb, nullptr,
                        E, HE, E, 0, 0, 0, E, 1.f, QC, nullptr, 0);
            }
        }
    }

    // ---- emit in the probed dtype (fallback tiers only) ----
    emit_out<<<dim3((unsigned)((NX / 8 + 255) / 256)), blk, 0, stream>>>(
        Ofin, d_out, NX, flag);
}